// Round 13
// baseline (320.833 us; speedup 1.0000x reference)
//
#include <hip/hip_runtime.h>

// PhaMPN v13: v12 + non-temporal hints on all zero-reuse streams, so the
// per-XCD L2s retain the fp8 msg gather table instead of stream pollution.
//   binput = fedges @ W_i (MFMA, stored bf16); msg = fp8(sigmoid(binput))
//   5x: msg = fp8(sigmoid(binput + (sum_8 msg[egraph]) @ W_h))   [k_iter]
//   hidden = bf16(sigmoid([feat|nei] @ W_o + b_o))               [k_final]
//   out = segment-mean(hidden), f32
// Numerics bit-identical to v12 (absmax 0.015625).

typedef __attribute__((ext_vector_type(4))) float f32x4;
typedef __attribute__((ext_vector_type(2))) float f32x2;
typedef __attribute__((ext_vector_type(8))) short s16x8;
typedef __attribute__((ext_vector_type(4))) unsigned u32x4;
typedef __attribute__((ext_vector_type(2))) unsigned u32x2;
typedef unsigned short u16;
typedef unsigned char u8;

constexpr int Nn   = 50000;
constexpr int Ee   = 150000;
constexpr int NBn  = 8;
constexpr int Hh   = 128;
constexpr int FFn  = 40;
constexpr int Bm   = 500;
constexpr int ITERS = 5;       // DEPTH - 1
constexpr int KP   = 136;      // nei-tile bf16 row stride (k_iter)
constexpr int KI   = 72;       // fedges-tile stride (K padded 41->64)
constexpr int KO   = 200;      // k_final A-tile stride (K padded 168->192)
constexpr int ACCW = 132;      // f32 acc stride (k_binput / k_final)
constexpr int ACC2 = 130;      // f32 acc stride (k_iter halves)

__device__ __forceinline__ float sigmoidf_(float x) {
    return 1.0f / (1.0f + __expf(-x));
}
// f32 -> bf16 round-to-nearest-even (finite values only)
__device__ __forceinline__ u16 f2bf(float f) {
    unsigned u = __float_as_uint(f);
    u += 0x7fffu + ((u >> 16) & 1u);
    return (u16)(u >> 16);
}
__device__ __forceinline__ float bflo(unsigned u) { return __uint_as_float(u << 16); }
__device__ __forceinline__ float bfhi(unsigned u) { return __uint_as_float(u & 0xffff0000u); }
__device__ __forceinline__ float bf1(u16 h) { return __uint_as_float(((unsigned)h) << 16); }
__device__ __forceinline__ unsigned pack2(float x, float y) {
    return (unsigned)f2bf(x) | ((unsigned)f2bf(y) << 16);
}
// fp8 e4m3 (OCP on gfx950) HW converts
__device__ __forceinline__ void add8f8(float* a, uint2 v) {
    f32x2 p;
    p = __builtin_amdgcn_cvt_pk_f32_fp8((int)v.x, false); a[0] += p[0]; a[1] += p[1];
    p = __builtin_amdgcn_cvt_pk_f32_fp8((int)v.x, true);  a[2] += p[0]; a[3] += p[1];
    p = __builtin_amdgcn_cvt_pk_f32_fp8((int)v.y, false); a[4] += p[0]; a[5] += p[1];
    p = __builtin_amdgcn_cvt_pk_f32_fp8((int)v.y, true);  a[6] += p[0]; a[7] += p[1];
}
__device__ __forceinline__ unsigned pack4f8(float a, float b, float c, float d) {
    int r = 0;
    r = __builtin_amdgcn_cvt_pk_fp8_f32(a, b, r, false);
    r = __builtin_amdgcn_cvt_pk_fp8_f32(c, d, r, true);
    return (unsigned)r;
}
// non-temporal vector helpers (streaming, zero-reuse traffic)
__device__ __forceinline__ uint4 ntld4(const void* p) {
    u32x4 v = __builtin_nontemporal_load((const u32x4*)p);
    return make_uint4(v.x, v.y, v.z, v.w);
}
__device__ __forceinline__ void ntst4(void* p, uint4 v) {
    u32x4 t = (u32x4){v.x, v.y, v.z, v.w};
    __builtin_nontemporal_store(t, (u32x4*)p);
}
__device__ __forceinline__ void ntst2(void* p, uint2 v) {
    u32x2 t = (u32x2){v.x, v.y};
    __builtin_nontemporal_store(t, (u32x2*)p);
}

// ---------------------------------------------------------------------------
// Fragment-major weights: flat i -> f=i>>9, l=(i>>3)&63, e=i&7; ks=f>>3, c=f&7;
// k = ks*32 + (l>>4)*8 + e; n = c*16 + (l&15).
// MFMA B-read: ((s16x8*)W)[f*64 + lane]  (lane-linear 1KB/instr, cacheable).
// ---------------------------------------------------------------------------
__global__ __launch_bounds__(256) void k_prep1(
    const float* __restrict__ W_h, const float* __restrict__ W_i,
    u16* __restrict__ wt_h, u16* __restrict__ wt_i)
{
    int i = blockIdx.x * 256 + threadIdx.x;
    if (i < Hh * Hh) {                       // wt_h: 32 frags
        int f = i >> 9, l = (i >> 3) & 63, e = i & 7;
        int ks = f >> 3, c = f & 7;
        int k = ks * 32 + (l >> 4) * 8 + e, n = c * 16 + (l & 15);
        wt_h[i] = f2bf(W_h[k * Hh + n]);
    } else {
        int j = i - Hh * Hh;
        if (j < 16 * 512) {                  // wt_i: 16 frags, k<41 else 0
            int f = j >> 9, l = (j >> 3) & 63, e = j & 7;
            int ks = f >> 3, c = f & 7;
            int k = ks * 32 + (l >> 4) * 8 + e, n = c * 16 + (l & 15);
            wt_i[j] = (k < 41) ? f2bf(W_i[k * Hh + n]) : (u16)0;
        }
    }
}

// wt_o: 48 frags; k<40 -> W_o[k][n]; 40..63 -> 0; 64..191 -> W_o[k-24][n]
__global__ __launch_bounds__(256) void k_prep2(
    const float* __restrict__ W_o, u16* __restrict__ wt_o)
{
    int i = blockIdx.x * 256 + threadIdx.x;
    if (i < 48 * 512) {
        int f = i >> 9, l = (i >> 3) & 63, e = i & 7;
        int ks = f >> 3, c = f & 7;
        int k = ks * 32 + (l >> 4) * 8 + e, n = c * 16 + (l & 15);
        u16 v = 0;
        if (k < FFn)                 v = f2bf(W_o[k * Hh + n]);
        else if (k >= 64 && k < 192) v = f2bf(W_o[(k - 24) * Hh + n]);
        wt_o[i] = v;
    }
}

// ---------------------------------------------------------------------------
// k_binput (MFMA, 512 thr): binput_bf = bf16(fedges @ W_i); msg = fp8(sigmoid)
// fedges loads + binput stores are non-temporal (zero reuse in this kernel;
// msg stores stay cached -- iteration 0 gathers from them next).
// ---------------------------------------------------------------------------
union BinSmem {
    struct { u16 Wi[16 * 512]; u16 A[Hh * KI]; } s;  // 16384 + 18432 B
    float acc[Hh][ACCW];                             // 67584 B
};

__global__ __launch_bounds__(512, 4) void k_binput(
    const float* __restrict__ fedges, const u16* __restrict__ wt_i,
    u16* __restrict__ binput_bf, u8* __restrict__ msg)
{
    __shared__ BinSmem u;
    const int t = threadIdx.x;
    const int row0 = blockIdx.x * 128;
    const int nvalid = min(128, Ee - row0);

    {
        uint4 z = make_uint4(0, 0, 0, 0);
        for (int i = t; i < Hh * KI / 8; i += 512) {
            if (i < 1024) ((uint4*)u.s.Wi)[i] = ((const uint4*)wt_i)[i];
            ((uint4*)u.s.A)[i] = z;
        }
    }
    __syncthreads();
    for (int i = t; i < nvalid * 41; i += 512) {
        int r = i / 41, k = i - r * 41;
        float fv = __builtin_nontemporal_load(&fedges[(size_t)row0 * 41 + i]);
        u.s.A[r * KI + k] = f2bf(fv);
    }
    __syncthreads();

    const int lane = t & 63, wid = t >> 6, l15 = lane & 15, l4 = lane >> 4;
    f32x4 acc[8];
    #pragma unroll
    for (int b = 0; b < 8; ++b) acc[b] = (f32x4){0.f, 0.f, 0.f, 0.f};

    #pragma unroll
    for (int ks = 0; ks < 2; ++ks) {
        s16x8 a = *(const s16x8*)&u.s.A[(wid * 16 + l15) * KI + ks * 32 + l4 * 8];
        #pragma unroll
        for (int c = 0; c < 8; ++c) {
            s16x8 b = ((const s16x8*)u.s.Wi)[(ks * 8 + c) * 64 + lane];
            acc[c] = __builtin_amdgcn_mfma_f32_16x16x32_bf16(a, b, acc[c], 0, 0, 0);
        }
    }
    __syncthreads();

    #pragma unroll
    for (int c = 0; c < 8; ++c)
        #pragma unroll
        for (int j = 0; j < 4; ++j)
            u.acc[wid * 16 + l4 * 4 + j][c * 16 + l15] = acc[c][j];
    __syncthreads();

    for (int i = t; i < Hh * 16; i += 512) {
        int row = i >> 4, seg = i & 15, grow = row0 + row;
        if (grow < Ee) {
            float4 a0 = *(const float4*)&u.acc[row][seg * 8];
            float4 a1 = *(const float4*)&u.acc[row][seg * 8 + 4];
            size_t o = (size_t)grow * Hh + seg * 8;
            uint4 bv;
            bv.x = pack2(a0.x, a0.y); bv.y = pack2(a0.z, a0.w);
            bv.z = pack2(a1.x, a1.y); bv.w = pack2(a1.z, a1.w);
            ntst4(&binput_bf[o], bv);
            uint2 m;
            m.x = pack4f8(sigmoidf_(a0.x), sigmoidf_(a0.y),
                          sigmoidf_(a0.z), sigmoidf_(a0.w));
            m.y = pack4f8(sigmoidf_(a1.x), sigmoidf_(a1.y),
                          sigmoidf_(a1.z), sigmoidf_(a1.w));
            *(uint2*)&msg[o] = m;   // fp8 row = 128 B (cached: gathered next)
        }
    }
}

// ---------------------------------------------------------------------------
// k_iter (MFMA, 256 thr, 64 rows): msg_out = fp8(sigmoid(binput + nei@W_h))
// Gather loads stay CACHED (the reuse we want L2 to keep).  egraph staging
// and binput epilogue loads are NON-TEMPORAL (pure streams, zero reuse).
// LDS: union(N 17408 B | acc32 16640 B) + sEG 2 KB = 19.4 KB.
// ---------------------------------------------------------------------------
union IterSmem {
    u16 N[64 * KP];             // 17408 B
    float acc[32][ACC2];        // 16640 B
};

__global__ __launch_bounds__(256, 4) void k_iter(
    const u8* __restrict__ msg_in, const int* __restrict__ egraph,
    const u16* __restrict__ wt_h, const u16* __restrict__ binput_bf,
    u8* __restrict__ msg_out)
{
    __shared__ IterSmem u;
    __shared__ int sEG[64 * NBn];   // 2048 B
    const int t = threadIdx.x;
    const int row0 = blockIdx.x * 64;
    const int lane = t & 63, wid = t >> 6, l15 = lane & 15, l4 = lane >> 4;

    if (t < 128) {
        int r = row0 + (t >> 1);
        uint4 v = make_uint4(0, 0, 0, 0);
        if (r < Ee) v = ntld4(&((const int4*)egraph)[r * 2 + (t & 1)]);
        ((uint4*)sEG)[t] = v;
    }
    __syncthreads();

    // gather: 16 lanes/row x 8B fp8; 16 rows per pass, 4 passes (cached loads)
    {
        const int s = t & 15, rl = t >> 4;
        #pragma unroll 2
        for (int pass = 0; pass < 4; ++pass) {
            int r = pass * 16 + rl;
            int grow = row0 + r;
            float a[8] = {0.f, 0.f, 0.f, 0.f, 0.f, 0.f, 0.f, 0.f};
            if (grow < Ee) {
                #pragma unroll
                for (int j = 0; j < NBn; ++j) {
                    int idx = sEG[r * NBn + j];
                    uint2 v = *(const uint2*)(msg_in + (size_t)idx * Hh + s * 8);
                    add8f8(a, v);
                }
            }
            uint4 o;
            o.x = pack2(a[0], a[1]); o.y = pack2(a[2], a[3]);
            o.z = pack2(a[4], a[5]); o.w = pack2(a[6], a[7]);
            *(uint4*)&u.N[r * KP + s * 8] = o;
        }
    }
    __syncthreads();

    // MFMA: A from LDS (rows wid*16..+15), B from global frag-major table
    f32x4 acc[8];
    #pragma unroll
    for (int b = 0; b < 8; ++b) acc[b] = (f32x4){0.f, 0.f, 0.f, 0.f};
    #pragma unroll
    for (int ks = 0; ks < 4; ++ks) {
        s16x8 a = *(const s16x8*)&u.N[(wid * 16 + l15) * KP + ks * 32 + l4 * 8];
        #pragma unroll
        for (int c = 0; c < 8; ++c) {
            s16x8 b = ((const s16x8*)wt_h)[(ks * 8 + c) * 64 + lane];
            acc[c] = __builtin_amdgcn_mfma_f32_16x16x32_bf16(a, b, acc[c], 0, 0, 0);
        }
    }
    __syncthreads();   // all LDS A-reads done -> union region reusable

    // epilogue: two 32-row halves; binput load nt, msg_out store cached
    #pragma unroll
    for (int h = 0; h < 2; ++h) {
        if ((wid >> 1) == h) {
            #pragma unroll
            for (int c = 0; c < 8; ++c)
                #pragma unroll
                for (int j = 0; j < 4; ++j)
                    u.acc[(wid & 1) * 16 + l4 * 4 + j][c * 16 + l15] = acc[c][j];
        }
        __syncthreads();
        for (int i = t; i < 32 * 16; i += 256) {
            int r = i >> 4, seg = i & 15;
            int g = row0 + h * 32 + r;
            if (g < Ee) {
                float4 a0 = *(const float4*)&u.acc[r][seg * 8];
                float4 a1 = *(const float4*)&u.acc[r][seg * 8 + 4];
                size_t o = (size_t)g * Hh + seg * 8;
                uint4 bv = ntld4(&binput_bf[o]);
                uint2 m;
                m.x = pack4f8(sigmoidf_(a0.x + bflo(bv.x)), sigmoidf_(a0.y + bfhi(bv.x)),
                              sigmoidf_(a0.z + bflo(bv.y)), sigmoidf_(a0.w + bfhi(bv.y)));
                m.y = pack4f8(sigmoidf_(a1.x + bflo(bv.z)), sigmoidf_(a1.y + bfhi(bv.z)),
                              sigmoidf_(a1.z + bflo(bv.w)), sigmoidf_(a1.w + bfhi(bv.w)));
                *(uint2*)&msg_out[o] = m;   // cached: next iter's gather table
            }
        }
        __syncthreads();
    }
}

// ---------------------------------------------------------------------------
// k_final (MFMA, 256 thr, 64 rows): hidden = bf16(sigmoid([feat|0|nei]@W_o+b))
// fp8 gather (cached); features nt; B from GLOBAL frag-major wt_o.
// ---------------------------------------------------------------------------
union FinSmem {
    u16 A[64 * KO];         // 25600 B
    float acc[64][ACCW];    // 33792 B
};

__global__ __launch_bounds__(256, 4) void k_final(
    const u8* __restrict__ msg_in, const int* __restrict__ agraph,
    const float* __restrict__ features, const u16* __restrict__ wt_o,
    const float* __restrict__ b_o, u16* __restrict__ hidden)
{
    __shared__ FinSmem u;
    __shared__ int sAG[64 * NBn];   // 2048 B
    __shared__ float sBias[Hh];     // 512 B
    const int t = threadIdx.x;
    const int row0 = blockIdx.x * 64;
    const int nvalid = min(64, Nn - row0);

    {
        uint4 z = make_uint4(0, 0, 0, 0);
        for (int i = t; i < 64 * KO / 8; i += 256) ((uint4*)u.A)[i] = z;
    }
    if (t < 128) {
        int r = row0 + (t >> 1);
        uint4 v = make_uint4(0, 0, 0, 0);
        if (r < Nn) v = ntld4(&((const int4*)agraph)[r * 2 + (t & 1)]);
        ((uint4*)sAG)[t] = v;
    }
    if (t < Hh / 4) ((float4*)sBias)[t] = ((const float4*)b_o)[t];
    __syncthreads();

    for (int i = t; i < nvalid * FFn; i += 256) {
        int r = i / FFn, k = i - r * FFn;
        float fv = __builtin_nontemporal_load(&features[(size_t)row0 * FFn + i]);
        u.A[r * KO + k] = f2bf(fv);
    }
    {
        const int s = t & 15, rl = t >> 4;
        #pragma unroll 2
        for (int pass = 0; pass < 4; ++pass) {
            int r = pass * 16 + rl;
            int grow = row0 + r;
            float a[8] = {0.f, 0.f, 0.f, 0.f, 0.f, 0.f, 0.f, 0.f};
            if (grow < Nn) {
                #pragma unroll
                for (int j = 0; j < NBn; ++j) {
                    int idx = sAG[r * NBn + j];
                    uint2 v = *(const uint2*)(msg_in + (size_t)idx * Hh + s * 8);
                    add8f8(a, v);
                }
            }
            uint4 o;
            o.x = pack2(a[0], a[1]); o.y = pack2(a[2], a[3]);
            o.z = pack2(a[4], a[5]); o.w = pack2(a[6], a[7]);
            *(uint4*)&u.A[r * KO + 64 + s * 8] = o;
        }
    }
    __syncthreads();

    const int lane = t & 63, wid = t >> 6, l15 = lane & 15, l4 = lane >> 4;
    f32x4 acc[8];
    #pragma unroll
    for (int b = 0; b < 8; ++b) acc[b] = (f32x4){0.f, 0.f, 0.f, 0.f};

    #pragma unroll
    for (int ks = 0; ks < 6; ++ks) {
        s16x8 a = *(const s16x8*)&u.A[(wid * 16 + l15) * KO + ks * 32 + l4 * 8];
        #pragma unroll
        for (int c = 0; c < 8; ++c) {
            s16x8 b = ((const s16x8*)wt_o)[(ks * 8 + c) * 64 + lane];
            acc[c] = __builtin_amdgcn_mfma_f32_16x16x32_bf16(a, b, acc[c], 0, 0, 0);
        }
    }
    __syncthreads();   // A reads done -> union reusable

    #pragma unroll
    for (int c = 0; c < 8; ++c)
        #pragma unroll
        for (int j = 0; j < 4; ++j)
            u.acc[wid * 16 + l4 * 4 + j][c * 16 + l15] = acc[c][j];
    __syncthreads();

    for (int i = t; i < 64 * 16; i += 256) {
        int r = i >> 4, seg = i & 15, g = row0 + r;
        if (g < Nn) {
            float4 a0 = *(const float4*)&u.acc[r][seg * 8];
            float4 a1 = *(const float4*)&u.acc[r][seg * 8 + 4];
            const float* bb = &sBias[seg * 8];
            uint4 m;
            m.x = pack2(sigmoidf_(a0.x + bb[0]), sigmoidf_(a0.y + bb[1]));
            m.y = pack2(sigmoidf_(a0.z + bb[2]), sigmoidf_(a0.w + bb[3]));
            m.z = pack2(sigmoidf_(a1.x + bb[4]), sigmoidf_(a1.y + bb[5]));
            m.w = pack2(sigmoidf_(a1.z + bb[6]), sigmoidf_(a1.w + bb[7]));
            *(uint4*)&hidden[(size_t)g * Hh + seg * 8] = m;  // cached: k_pool next
        }
    }
}

// ---------------------------------------------------------------------------
// k_pool: segment mean over bf16 hidden. One block (128 threads) / molecule.
// ---------------------------------------------------------------------------
__global__ __launch_bounds__(128) void k_pool(
    const u16* __restrict__ hidden, const int* __restrict__ scope,
    float* __restrict__ out)
{
    const int b = blockIdx.x;
    const int t = threadIdx.x;
    const int start = scope[b * 2 + 0];
    const int len   = scope[b * 2 + 1];
    float acc = 0.f;
    for (int i = 0; i < len; ++i)
        acc += bf1(hidden[(size_t)(start + i) * Hh + t]);
    out[(size_t)b * Hh + t] = acc / (float)len;
}

// ---------------------------------------------------------------------------
extern "C" void kernel_launch(void* const* d_in, const int* in_sizes, int n_in,
                              void* d_out, int out_size, void* d_ws, size_t ws_size,
                              hipStream_t stream)
{
    const float* features = (const float*)d_in[0];
    const float* fedges   = (const float*)d_in[1];
    const int*   agraph   = (const int*)d_in[2];
    const int*   egraph   = (const int*)d_in[3];
    const int*   scope    = (const int*)d_in[4];
    const float* W_i      = (const float*)d_in[5];
    const float* W_h      = (const float*)d_in[6];
    const float* W_o      = (const float*)d_in[7];
    const float* b_o      = (const float*)d_in[8];
    float* out = (float*)d_out;

    // Workspace: binput bf16[E*128] | msg0 fp8[E*128] | msg1 fp8[E*128] | wt_h.
    // wt_i parks in msg1 (consumed by k_binput before iter0 writes msg1);
    // wt_o parks in binput region (prepped after the last k_iter);
    // hidden (bf16, 12.8 MB) lives in the final free fp8 plane (msg0, 19.2 MB).
    const size_t plane = (size_t)Ee * Hh;    // elements per plane
    u16* binput_bf = (u16*)d_ws;
    u8*  msg0 = (u8*)(binput_bf + plane);
    u8*  msg1 = msg0 + plane;
    u16* wt_h = (u16*)(msg1 + plane);        // 16384 u16
    u16* wt_i = (u16*)msg1;                  // 8192 u16 (parked)
    u16* wt_o = binput_bf;                   // 24576 u16 (parked, used last)

    k_prep1<<<(Hh * Hh + 16 * 512 + 255) / 256, 256, 0, stream>>>(W_h, W_i, wt_h, wt_i);

    k_binput<<<(Ee + 127) / 128, 512, 0, stream>>>(fedges, wt_i, binput_bf, msg0);

    const int eblocks64 = (Ee + 63) / 64;
    u8* src = msg0;
    u8* dst = msg1;
    for (int d = 0; d < ITERS; ++d) {
        k_iter<<<eblocks64, 256, 0, stream>>>(src, egraph, wt_h, binput_bf, dst);
        u8* tmp = src; src = dst; dst = tmp;
    }
    // final message in `src` (= msg1); binput now dead -> prep wt_o there.
    k_prep2<<<(48 * 512) / 256, 256, 0, stream>>>(W_o, wt_o);

    u16* hidden = (u16*)dst;   // = msg0 region (free, 19.2 MB >= 12.8 MB)
    const int nblocks = (Nn + 63) / 64;
    k_final<<<nblocks, 256, 0, stream>>>(src, agraph, features, wt_o, b_o, hidden);

    k_pool<<<Bm, 128, 0, stream>>>(hidden, scope, out);
}

// Round 14
// 314.784 us; speedup vs baseline: 1.0192x; 1.0192x over previous
//
#include <hip/hip_runtime.h>

// PhaMPN v14: v12 (best: 291.6us) + k_iter epilogue-binput register preload.
//   binput = fedges @ W_i (MFMA, stored bf16); msg = fp8(sigmoid(binput))
//   5x: msg = fp8(sigmoid(binput + (sum_8 msg[egraph]) @ W_h))   [k_iter]
//   hidden = bf16(sigmoid([feat|nei] @ W_o + b_o))               [k_final]
//   out = segment-mean(hidden), f32
// v14: binput values needed by k_iter's epilogue are preloaded into registers
//      BEFORE the gather phase (latency hides under the gather's outstanding
//      loads).  No nt hints (v13 regression).  Numerics identical to v10/v12.

typedef __attribute__((ext_vector_type(4))) float f32x4;
typedef __attribute__((ext_vector_type(2))) float f32x2;
typedef __attribute__((ext_vector_type(8))) short s16x8;
typedef unsigned short u16;
typedef unsigned char u8;

constexpr int Nn   = 50000;
constexpr int Ee   = 150000;
constexpr int NBn  = 8;
constexpr int Hh   = 128;
constexpr int FFn  = 40;
constexpr int Bm   = 500;
constexpr int ITERS = 5;       // DEPTH - 1
constexpr int KP   = 136;      // nei-tile bf16 row stride (k_iter)
constexpr int KI   = 72;       // fedges-tile stride (K padded 41->64)
constexpr int KO   = 200;      // k_final A-tile stride (K padded 168->192)
constexpr int ACCW = 132;      // f32 acc stride (k_binput / k_final)
constexpr int ACC2 = 130;      // f32 acc stride (k_iter halves)

__device__ __forceinline__ float sigmoidf_(float x) {
    return 1.0f / (1.0f + __expf(-x));
}
// f32 -> bf16 round-to-nearest-even (finite values only)
__device__ __forceinline__ u16 f2bf(float f) {
    unsigned u = __float_as_uint(f);
    u += 0x7fffu + ((u >> 16) & 1u);
    return (u16)(u >> 16);
}
__device__ __forceinline__ float bflo(unsigned u) { return __uint_as_float(u << 16); }
__device__ __forceinline__ float bfhi(unsigned u) { return __uint_as_float(u & 0xffff0000u); }
__device__ __forceinline__ float bf1(u16 h) { return __uint_as_float(((unsigned)h) << 16); }
__device__ __forceinline__ unsigned pack2(float x, float y) {
    return (unsigned)f2bf(x) | ((unsigned)f2bf(y) << 16);
}
// fp8 e4m3 (OCP on gfx950) HW converts
__device__ __forceinline__ void add8f8(float* a, uint2 v) {
    f32x2 p;
    p = __builtin_amdgcn_cvt_pk_f32_fp8((int)v.x, false); a[0] += p[0]; a[1] += p[1];
    p = __builtin_amdgcn_cvt_pk_f32_fp8((int)v.x, true);  a[2] += p[0]; a[3] += p[1];
    p = __builtin_amdgcn_cvt_pk_f32_fp8((int)v.y, false); a[4] += p[0]; a[5] += p[1];
    p = __builtin_amdgcn_cvt_pk_f32_fp8((int)v.y, true);  a[6] += p[0]; a[7] += p[1];
}
__device__ __forceinline__ unsigned pack4f8(float a, float b, float c, float d) {
    int r = 0;
    r = __builtin_amdgcn_cvt_pk_fp8_f32(a, b, r, false);
    r = __builtin_amdgcn_cvt_pk_fp8_f32(c, d, r, true);
    return (unsigned)r;
}

// ---------------------------------------------------------------------------
// Fragment-major weights: flat i -> f=i>>9, l=(i>>3)&63, e=i&7; ks=f>>3, c=f&7;
// k = ks*32 + (l>>4)*8 + e; n = c*16 + (l&15).
// MFMA B-read: ((s16x8*)W)[f*64 + lane]  (lane-linear 1KB/instr, cacheable).
// ---------------------------------------------------------------------------
__global__ __launch_bounds__(256) void k_prep1(
    const float* __restrict__ W_h, const float* __restrict__ W_i,
    u16* __restrict__ wt_h, u16* __restrict__ wt_i)
{
    int i = blockIdx.x * 256 + threadIdx.x;
    if (i < Hh * Hh) {                       // wt_h: 32 frags
        int f = i >> 9, l = (i >> 3) & 63, e = i & 7;
        int ks = f >> 3, c = f & 7;
        int k = ks * 32 + (l >> 4) * 8 + e, n = c * 16 + (l & 15);
        wt_h[i] = f2bf(W_h[k * Hh + n]);
    } else {
        int j = i - Hh * Hh;
        if (j < 16 * 512) {                  // wt_i: 16 frags, k<41 else 0
            int f = j >> 9, l = (j >> 3) & 63, e = j & 7;
            int ks = f >> 3, c = f & 7;
            int k = ks * 32 + (l >> 4) * 8 + e, n = c * 16 + (l & 15);
            wt_i[j] = (k < 41) ? f2bf(W_i[k * Hh + n]) : (u16)0;
        }
    }
}

// wt_o: 48 frags; k<40 -> W_o[k][n]; 40..63 -> 0; 64..191 -> W_o[k-24][n]
__global__ __launch_bounds__(256) void k_prep2(
    const float* __restrict__ W_o, u16* __restrict__ wt_o)
{
    int i = blockIdx.x * 256 + threadIdx.x;
    if (i < 48 * 512) {
        int f = i >> 9, l = (i >> 3) & 63, e = i & 7;
        int ks = f >> 3, c = f & 7;
        int k = ks * 32 + (l >> 4) * 8 + e, n = c * 16 + (l & 15);
        u16 v = 0;
        if (k < FFn)                 v = f2bf(W_o[k * Hh + n]);
        else if (k >= 64 && k < 192) v = f2bf(W_o[(k - 24) * Hh + n]);
        wt_o[i] = v;
    }
}

// ---------------------------------------------------------------------------
// k_binput (MFMA, 512 thr): binput_bf = bf16(fedges @ W_i); msg = fp8(sigmoid)
// ---------------------------------------------------------------------------
union BinSmem {
    struct { u16 Wi[16 * 512]; u16 A[Hh * KI]; } s;  // 16384 + 18432 B
    float acc[Hh][ACCW];                             // 67584 B
};

__global__ __launch_bounds__(512, 4) void k_binput(
    const float* __restrict__ fedges, const u16* __restrict__ wt_i,
    u16* __restrict__ binput_bf, u8* __restrict__ msg)
{
    __shared__ BinSmem u;
    const int t = threadIdx.x;
    const int row0 = blockIdx.x * 128;
    const int nvalid = min(128, Ee - row0);

    {
        uint4 z = make_uint4(0, 0, 0, 0);
        for (int i = t; i < Hh * KI / 8; i += 512) {
            if (i < 1024) ((uint4*)u.s.Wi)[i] = ((const uint4*)wt_i)[i];
            ((uint4*)u.s.A)[i] = z;
        }
    }
    __syncthreads();
    for (int i = t; i < nvalid * 41; i += 512) {
        int r = i / 41, k = i - r * 41;
        u.s.A[r * KI + k] = f2bf(fedges[(size_t)row0 * 41 + i]);
    }
    __syncthreads();

    const int lane = t & 63, wid = t >> 6, l15 = lane & 15, l4 = lane >> 4;
    f32x4 acc[8];
    #pragma unroll
    for (int b = 0; b < 8; ++b) acc[b] = (f32x4){0.f, 0.f, 0.f, 0.f};

    #pragma unroll
    for (int ks = 0; ks < 2; ++ks) {
        s16x8 a = *(const s16x8*)&u.s.A[(wid * 16 + l15) * KI + ks * 32 + l4 * 8];
        #pragma unroll
        for (int c = 0; c < 8; ++c) {
            s16x8 b = ((const s16x8*)u.s.Wi)[(ks * 8 + c) * 64 + lane];
            acc[c] = __builtin_amdgcn_mfma_f32_16x16x32_bf16(a, b, acc[c], 0, 0, 0);
        }
    }
    __syncthreads();

    #pragma unroll
    for (int c = 0; c < 8; ++c)
        #pragma unroll
        for (int j = 0; j < 4; ++j)
            u.acc[wid * 16 + l4 * 4 + j][c * 16 + l15] = acc[c][j];
    __syncthreads();

    for (int i = t; i < Hh * 16; i += 512) {
        int row = i >> 4, seg = i & 15, grow = row0 + row;
        if (grow < Ee) {
            float4 a0 = *(const float4*)&u.acc[row][seg * 8];
            float4 a1 = *(const float4*)&u.acc[row][seg * 8 + 4];
            size_t o = (size_t)grow * Hh + seg * 8;
            uint4 bv;
            bv.x = pack2(a0.x, a0.y); bv.y = pack2(a0.z, a0.w);
            bv.z = pack2(a1.x, a1.y); bv.w = pack2(a1.z, a1.w);
            *(uint4*)&binput_bf[o] = bv;
            uint2 m;
            m.x = pack4f8(sigmoidf_(a0.x), sigmoidf_(a0.y),
                          sigmoidf_(a0.z), sigmoidf_(a0.w));
            m.y = pack4f8(sigmoidf_(a1.x), sigmoidf_(a1.y),
                          sigmoidf_(a1.z), sigmoidf_(a1.w));
            *(uint2*)&msg[o] = m;   // fp8 row = 128 B
        }
    }
}

// ---------------------------------------------------------------------------
// k_iter (MFMA, 256 thr, 64 rows): msg_out = fp8(sigmoid(binput + nei@W_h))
// v12 structure; epilogue binput preloaded into registers before the gather
// (latency overlaps the gather's outstanding loads).  Statically-indexed
// pre[2][2] (rule: no runtime-indexed reg arrays).
// LDS: union(N 17408 B | acc32 16640 B) + sEG 2 KB = 19.4 KB.
// ---------------------------------------------------------------------------
union IterSmem {
    u16 N[64 * KP];             // 17408 B
    float acc[32][ACC2];        // 16640 B
};

__global__ __launch_bounds__(256, 4) void k_iter(
    const u8* __restrict__ msg_in, const int* __restrict__ egraph,
    const u16* __restrict__ wt_h, const u16* __restrict__ binput_bf,
    u8* __restrict__ msg_out)
{
    __shared__ IterSmem u;
    __shared__ int sEG[64 * NBn];   // 2048 B
    const int t = threadIdx.x;
    const int row0 = blockIdx.x * 64;
    const int lane = t & 63, wid = t >> 6, l15 = lane & 15, l4 = lane >> 4;

    if (t < 128) {
        int r = row0 + (t >> 1);
        int4 v = make_int4(0, 0, 0, 0);
        if (r < Ee) v = ((const int4*)egraph)[r * 2 + (t & 1)];
        ((int4*)sEG)[t] = v;
    }

    // preload the epilogue's binput values (2 halves x 2 strips per thread)
    uint4 pre[2][2];
    #pragma unroll
    for (int h = 0; h < 2; ++h)
        #pragma unroll
        for (int q = 0; q < 2; ++q) {
            int i = t + q * 256;
            int r = i >> 4, seg = i & 15;
            int g = row0 + h * 32 + r;
            pre[h][q] = (g < Ee)
                ? *(const uint4*)&binput_bf[(size_t)g * Hh + seg * 8]
                : make_uint4(0, 0, 0, 0);
        }
    __syncthreads();

    // gather: 16 lanes/row x 8B fp8; 16 rows per pass, 4 passes (v10 pattern)
    {
        const int s = t & 15, rl = t >> 4;
        #pragma unroll 2
        for (int pass = 0; pass < 4; ++pass) {
            int r = pass * 16 + rl;
            int grow = row0 + r;
            float a[8] = {0.f, 0.f, 0.f, 0.f, 0.f, 0.f, 0.f, 0.f};
            if (grow < Ee) {
                #pragma unroll
                for (int j = 0; j < NBn; ++j) {
                    int idx = sEG[r * NBn + j];
                    uint2 v = *(const uint2*)(msg_in + (size_t)idx * Hh + s * 8);
                    add8f8(a, v);
                }
            }
            uint4 o;
            o.x = pack2(a[0], a[1]); o.y = pack2(a[2], a[3]);
            o.z = pack2(a[4], a[5]); o.w = pack2(a[6], a[7]);
            *(uint4*)&u.N[r * KP + s * 8] = o;
        }
    }
    __syncthreads();

    // MFMA: A from LDS (rows wid*16..+15), B from global frag-major table
    f32x4 acc[8];
    #pragma unroll
    for (int b = 0; b < 8; ++b) acc[b] = (f32x4){0.f, 0.f, 0.f, 0.f};
    #pragma unroll
    for (int ks = 0; ks < 4; ++ks) {
        s16x8 a = *(const s16x8*)&u.N[(wid * 16 + l15) * KP + ks * 32 + l4 * 8];
        #pragma unroll
        for (int c = 0; c < 8; ++c) {
            s16x8 b = ((const s16x8*)wt_h)[(ks * 8 + c) * 64 + lane];
            acc[c] = __builtin_amdgcn_mfma_f32_16x16x32_bf16(a, b, acc[c], 0, 0, 0);
        }
    }
    __syncthreads();   // all LDS A-reads done -> union region reusable

    // epilogue: two 32-row halves through the union acc buffer; binput from regs
    #pragma unroll
    for (int h = 0; h < 2; ++h) {
        if ((wid >> 1) == h) {
            #pragma unroll
            for (int c = 0; c < 8; ++c)
                #pragma unroll
                for (int j = 0; j < 4; ++j)
                    u.acc[(wid & 1) * 16 + l4 * 4 + j][c * 16 + l15] = acc[c][j];
        }
        __syncthreads();
        #pragma unroll
        for (int q = 0; q < 2; ++q) {
            int i = t + q * 256;
            int r = i >> 4, seg = i & 15;
            int g = row0 + h * 32 + r;
            if (g < Ee) {
                float4 a0 = *(const float4*)&u.acc[r][seg * 8];
                float4 a1 = *(const float4*)&u.acc[r][seg * 8 + 4];
                uint4 bv = pre[h][q];
                uint2 m;
                m.x = pack4f8(sigmoidf_(a0.x + bflo(bv.x)), sigmoidf_(a0.y + bfhi(bv.x)),
                              sigmoidf_(a0.z + bflo(bv.y)), sigmoidf_(a0.w + bfhi(bv.y)));
                m.y = pack4f8(sigmoidf_(a1.x + bflo(bv.z)), sigmoidf_(a1.y + bfhi(bv.z)),
                              sigmoidf_(a1.z + bflo(bv.w)), sigmoidf_(a1.w + bfhi(bv.w)));
                *(uint2*)&msg_out[(size_t)g * Hh + seg * 8] = m;
            }
        }
        __syncthreads();
    }
}

// ---------------------------------------------------------------------------
// k_final (MFMA, 256 thr, 64 rows): hidden = bf16(sigmoid([feat|0|nei]@W_o+b))
// fp8 gather; B from GLOBAL frag-major wt_o.  (unchanged from v12)
// ---------------------------------------------------------------------------
union FinSmem {
    u16 A[64 * KO];         // 25600 B
    float acc[64][ACCW];    // 33792 B
};

__global__ __launch_bounds__(256, 4) void k_final(
    const u8* __restrict__ msg_in, const int* __restrict__ agraph,
    const float* __restrict__ features, const u16* __restrict__ wt_o,
    const float* __restrict__ b_o, u16* __restrict__ hidden)
{
    __shared__ FinSmem u;
    __shared__ int sAG[64 * NBn];   // 2048 B
    __shared__ float sBias[Hh];     // 512 B
    const int t = threadIdx.x;
    const int row0 = blockIdx.x * 64;
    const int nvalid = min(64, Nn - row0);

    {
        uint4 z = make_uint4(0, 0, 0, 0);
        for (int i = t; i < 64 * KO / 8; i += 256) ((uint4*)u.A)[i] = z;
    }
    if (t < 128) {
        int r = row0 + (t >> 1);
        int4 v = make_int4(0, 0, 0, 0);
        if (r < Nn) v = ((const int4*)agraph)[r * 2 + (t & 1)];
        ((int4*)sAG)[t] = v;
    }
    if (t < Hh / 4) ((float4*)sBias)[t] = ((const float4*)b_o)[t];
    __syncthreads();

    for (int i = t; i < nvalid * FFn; i += 256) {
        int r = i / FFn, k = i - r * FFn;
        u.A[r * KO + k] = f2bf(features[(size_t)row0 * FFn + i]);
    }
    {
        const int s = t & 15, rl = t >> 4;
        #pragma unroll 2
        for (int pass = 0; pass < 4; ++pass) {
            int r = pass * 16 + rl;
            int grow = row0 + r;
            float a[8] = {0.f, 0.f, 0.f, 0.f, 0.f, 0.f, 0.f, 0.f};
            if (grow < Nn) {
                #pragma unroll
                for (int j = 0; j < NBn; ++j) {
                    int idx = sAG[r * NBn + j];
                    uint2 v = *(const uint2*)(msg_in + (size_t)idx * Hh + s * 8);
                    add8f8(a, v);
                }
            }
            uint4 o;
            o.x = pack2(a[0], a[1]); o.y = pack2(a[2], a[3]);
            o.z = pack2(a[4], a[5]); o.w = pack2(a[6], a[7]);
            *(uint4*)&u.A[r * KO + 64 + s * 8] = o;
        }
    }
    __syncthreads();

    const int lane = t & 63, wid = t >> 6, l15 = lane & 15, l4 = lane >> 4;
    f32x4 acc[8];
    #pragma unroll
    for (int b = 0; b < 8; ++b) acc[b] = (f32x4){0.f, 0.f, 0.f, 0.f};

    #pragma unroll
    for (int ks = 0; ks < 6; ++ks) {
        s16x8 a = *(const s16x8*)&u.A[(wid * 16 + l15) * KO + ks * 32 + l4 * 8];
        #pragma unroll
        for (int c = 0; c < 8; ++c) {
            s16x8 b = ((const s16x8*)wt_o)[(ks * 8 + c) * 64 + lane];
            acc[c] = __builtin_amdgcn_mfma_f32_16x16x32_bf16(a, b, acc[c], 0, 0, 0);
        }
    }
    __syncthreads();   // A reads done -> union reusable

    #pragma unroll
    for (int c = 0; c < 8; ++c)
        #pragma unroll
        for (int j = 0; j < 4; ++j)
            u.acc[wid * 16 + l4 * 4 + j][c * 16 + l15] = acc[c][j];
    __syncthreads();

    for (int i = t; i < 64 * 16; i += 256) {
        int r = i >> 4, seg = i & 15, g = row0 + r;
        if (g < Nn) {
            float4 a0 = *(const float4*)&u.acc[r][seg * 8];
            float4 a1 = *(const float4*)&u.acc[r][seg * 8 + 4];
            const float* bb = &sBias[seg * 8];
            uint4 m;
            m.x = pack2(sigmoidf_(a0.x + bb[0]), sigmoidf_(a0.y + bb[1]));
            m.y = pack2(sigmoidf_(a0.z + bb[2]), sigmoidf_(a0.w + bb[3]));
            m.z = pack2(sigmoidf_(a1.x + bb[4]), sigmoidf_(a1.y + bb[5]));
            m.w = pack2(sigmoidf_(a1.z + bb[6]), sigmoidf_(a1.w + bb[7]));
            *(uint4*)&hidden[(size_t)g * Hh + seg * 8] = m;
        }
    }
}

// ---------------------------------------------------------------------------
// k_pool: segment mean over bf16 hidden. One block (128 threads) / molecule.
// ---------------------------------------------------------------------------
__global__ __launch_bounds__(128) void k_pool(
    const u16* __restrict__ hidden, const int* __restrict__ scope,
    float* __restrict__ out)
{
    const int b = blockIdx.x;
    const int t = threadIdx.x;
    const int start = scope[b * 2 + 0];
    const int len   = scope[b * 2 + 1];
    float acc = 0.f;
    for (int i = 0; i < len; ++i)
        acc += bf1(hidden[(size_t)(start + i) * Hh + t]);
    out[(size_t)b * Hh + t] = acc / (float)len;
}

// ---------------------------------------------------------------------------
extern "C" void kernel_launch(void* const* d_in, const int* in_sizes, int n_in,
                              void* d_out, int out_size, void* d_ws, size_t ws_size,
                              hipStream_t stream)
{
    const float* features = (const float*)d_in[0];
    const float* fedges   = (const float*)d_in[1];
    const int*   agraph   = (const int*)d_in[2];
    const int*   egraph   = (const int*)d_in[3];
    const int*   scope    = (const int*)d_in[4];
    const float* W_i      = (const float*)d_in[5];
    const float* W_h      = (const float*)d_in[6];
    const float* W_o      = (const float*)d_in[7];
    const float* b_o      = (const float*)d_in[8];
    float* out = (float*)d_out;

    // Workspace: binput bf16[E*128] | msg0 fp8[E*128] | msg1 fp8[E*128] | wt_h.
    // wt_i parks in msg1 (consumed by k_binput before iter0 writes msg1);
    // wt_o parks in binput region (prepped after the last k_iter);
    // hidden (bf16, 12.8 MB) lives in the final free fp8 plane (msg0, 19.2 MB).
    const size_t plane = (size_t)Ee * Hh;    // elements per plane
    u16* binput_bf = (u16*)d_ws;
    u8*  msg0 = (u8*)(binput_bf + plane);
    u8*  msg1 = msg0 + plane;
    u16* wt_h = (u16*)(msg1 + plane);        // 16384 u16
    u16* wt_i = (u16*)msg1;                  // 8192 u16 (parked)
    u16* wt_o = binput_bf;                   // 24576 u16 (parked, used last)

    k_prep1<<<(Hh * Hh + 16 * 512 + 255) / 256, 256, 0, stream>>>(W_h, W_i, wt_h, wt_i);

    k_binput<<<(Ee + 127) / 128, 512, 0, stream>>>(fedges, wt_i, binput_bf, msg0);

    const int eblocks64 = (Ee + 63) / 64;
    u8* src = msg0;
    u8* dst = msg1;
    for (int d = 0; d < ITERS; ++d) {
        k_iter<<<eblocks64, 256, 0, stream>>>(src, egraph, wt_h, binput_bf, dst);
        u8* tmp = src; src = dst; dst = tmp;
    }
    // final message in `src` (= msg1); binput now dead -> prep wt_o there.
    k_prep2<<<(48 * 512) / 256, 256, 0, stream>>>(W_o, wt_o);

    u16* hidden = (u16*)dst;   // = msg0 region (free, 19.2 MB >= 12.8 MB)
    const int nblocks = (Nn + 63) / 64;
    k_final<<<nblocks, 256, 0, stream>>>(src, agraph, features, wt_o, b_o, hidden);

    k_pool<<<Bm, 128, 0, stream>>>(hidden, scope, out);
}

// Round 15
// 291.374 us; speedup vs baseline: 1.1011x; 1.0803x over previous
//
#include <hip/hip_runtime.h>

// PhaMPN v15 == v12 (best measured: 291.6 us).  Reverts v14's preload (VGPR
// 40->56 cost ~2 resident blocks/CU; occupancy loss > latency-hiding gain).
//   binput = fedges @ W_i (MFMA, stored bf16); msg = fp8(sigmoid(binput))
//   5x: msg = fp8(sigmoid(binput + (sum_8 msg[egraph]) @ W_h))   [k_iter]
//   hidden = bf16(sigmoid([feat|nei] @ W_o + b_o))               [k_final]
//   out = segment-mean(hidden), f32
// k_iter floor evidence: identical 46us across occupancy 44-72%, two block
// shapes, nt hints, preload -- FETCH 84MB/iter = compulsory; gather-bound.

typedef __attribute__((ext_vector_type(4))) float f32x4;
typedef __attribute__((ext_vector_type(2))) float f32x2;
typedef __attribute__((ext_vector_type(8))) short s16x8;
typedef unsigned short u16;
typedef unsigned char u8;

constexpr int Nn   = 50000;
constexpr int Ee   = 150000;
constexpr int NBn  = 8;
constexpr int Hh   = 128;
constexpr int FFn  = 40;
constexpr int Bm   = 500;
constexpr int ITERS = 5;       // DEPTH - 1
constexpr int KP   = 136;      // nei-tile bf16 row stride (k_iter)
constexpr int KI   = 72;       // fedges-tile stride (K padded 41->64)
constexpr int KO   = 200;      // k_final A-tile stride (K padded 168->192)
constexpr int ACCW = 132;      // f32 acc stride (k_binput / k_final)
constexpr int ACC2 = 130;      // f32 acc stride (k_iter halves)

__device__ __forceinline__ float sigmoidf_(float x) {
    return 1.0f / (1.0f + __expf(-x));
}
// f32 -> bf16 round-to-nearest-even (finite values only)
__device__ __forceinline__ u16 f2bf(float f) {
    unsigned u = __float_as_uint(f);
    u += 0x7fffu + ((u >> 16) & 1u);
    return (u16)(u >> 16);
}
__device__ __forceinline__ float bflo(unsigned u) { return __uint_as_float(u << 16); }
__device__ __forceinline__ float bfhi(unsigned u) { return __uint_as_float(u & 0xffff0000u); }
__device__ __forceinline__ float bf1(u16 h) { return __uint_as_float(((unsigned)h) << 16); }
__device__ __forceinline__ unsigned pack2(float x, float y) {
    return (unsigned)f2bf(x) | ((unsigned)f2bf(y) << 16);
}
// fp8 e4m3 (OCP on gfx950) HW converts
__device__ __forceinline__ void add8f8(float* a, uint2 v) {
    f32x2 p;
    p = __builtin_amdgcn_cvt_pk_f32_fp8((int)v.x, false); a[0] += p[0]; a[1] += p[1];
    p = __builtin_amdgcn_cvt_pk_f32_fp8((int)v.x, true);  a[2] += p[0]; a[3] += p[1];
    p = __builtin_amdgcn_cvt_pk_f32_fp8((int)v.y, false); a[4] += p[0]; a[5] += p[1];
    p = __builtin_amdgcn_cvt_pk_f32_fp8((int)v.y, true);  a[6] += p[0]; a[7] += p[1];
}
__device__ __forceinline__ unsigned pack4f8(float a, float b, float c, float d) {
    int r = 0;
    r = __builtin_amdgcn_cvt_pk_fp8_f32(a, b, r, false);
    r = __builtin_amdgcn_cvt_pk_fp8_f32(c, d, r, true);
    return (unsigned)r;
}

// ---------------------------------------------------------------------------
// Fragment-major weights: flat i -> f=i>>9, l=(i>>3)&63, e=i&7; ks=f>>3, c=f&7;
// k = ks*32 + (l>>4)*8 + e; n = c*16 + (l&15).
// MFMA B-read: ((s16x8*)W)[f*64 + lane]  (lane-linear 1KB/instr, cacheable).
// ---------------------------------------------------------------------------
__global__ __launch_bounds__(256) void k_prep1(
    const float* __restrict__ W_h, const float* __restrict__ W_i,
    u16* __restrict__ wt_h, u16* __restrict__ wt_i)
{
    int i = blockIdx.x * 256 + threadIdx.x;
    if (i < Hh * Hh) {                       // wt_h: 32 frags
        int f = i >> 9, l = (i >> 3) & 63, e = i & 7;
        int ks = f >> 3, c = f & 7;
        int k = ks * 32 + (l >> 4) * 8 + e, n = c * 16 + (l & 15);
        wt_h[i] = f2bf(W_h[k * Hh + n]);
    } else {
        int j = i - Hh * Hh;
        if (j < 16 * 512) {                  // wt_i: 16 frags, k<41 else 0
            int f = j >> 9, l = (j >> 3) & 63, e = j & 7;
            int ks = f >> 3, c = f & 7;
            int k = ks * 32 + (l >> 4) * 8 + e, n = c * 16 + (l & 15);
            wt_i[j] = (k < 41) ? f2bf(W_i[k * Hh + n]) : (u16)0;
        }
    }
}

// wt_o: 48 frags; k<40 -> W_o[k][n]; 40..63 -> 0; 64..191 -> W_o[k-24][n]
__global__ __launch_bounds__(256) void k_prep2(
    const float* __restrict__ W_o, u16* __restrict__ wt_o)
{
    int i = blockIdx.x * 256 + threadIdx.x;
    if (i < 48 * 512) {
        int f = i >> 9, l = (i >> 3) & 63, e = i & 7;
        int ks = f >> 3, c = f & 7;
        int k = ks * 32 + (l >> 4) * 8 + e, n = c * 16 + (l & 15);
        u16 v = 0;
        if (k < FFn)                 v = f2bf(W_o[k * Hh + n]);
        else if (k >= 64 && k < 192) v = f2bf(W_o[(k - 24) * Hh + n]);
        wt_o[i] = v;
    }
}

// ---------------------------------------------------------------------------
// k_binput (MFMA, 512 thr): binput_bf = bf16(fedges @ W_i); msg = fp8(sigmoid)
// ---------------------------------------------------------------------------
union BinSmem {
    struct { u16 Wi[16 * 512]; u16 A[Hh * KI]; } s;  // 16384 + 18432 B
    float acc[Hh][ACCW];                             // 67584 B
};

__global__ __launch_bounds__(512, 4) void k_binput(
    const float* __restrict__ fedges, const u16* __restrict__ wt_i,
    u16* __restrict__ binput_bf, u8* __restrict__ msg)
{
    __shared__ BinSmem u;
    const int t = threadIdx.x;
    const int row0 = blockIdx.x * 128;
    const int nvalid = min(128, Ee - row0);

    {
        uint4 z = make_uint4(0, 0, 0, 0);
        for (int i = t; i < Hh * KI / 8; i += 512) {
            if (i < 1024) ((uint4*)u.s.Wi)[i] = ((const uint4*)wt_i)[i];
            ((uint4*)u.s.A)[i] = z;
        }
    }
    __syncthreads();
    for (int i = t; i < nvalid * 41; i += 512) {
        int r = i / 41, k = i - r * 41;
        u.s.A[r * KI + k] = f2bf(fedges[(size_t)row0 * 41 + i]);
    }
    __syncthreads();

    const int lane = t & 63, wid = t >> 6, l15 = lane & 15, l4 = lane >> 4;
    f32x4 acc[8];
    #pragma unroll
    for (int b = 0; b < 8; ++b) acc[b] = (f32x4){0.f, 0.f, 0.f, 0.f};

    #pragma unroll
    for (int ks = 0; ks < 2; ++ks) {
        s16x8 a = *(const s16x8*)&u.s.A[(wid * 16 + l15) * KI + ks * 32 + l4 * 8];
        #pragma unroll
        for (int c = 0; c < 8; ++c) {
            s16x8 b = ((const s16x8*)u.s.Wi)[(ks * 8 + c) * 64 + lane];
            acc[c] = __builtin_amdgcn_mfma_f32_16x16x32_bf16(a, b, acc[c], 0, 0, 0);
        }
    }
    __syncthreads();

    #pragma unroll
    for (int c = 0; c < 8; ++c)
        #pragma unroll
        for (int j = 0; j < 4; ++j)
            u.acc[wid * 16 + l4 * 4 + j][c * 16 + l15] = acc[c][j];
    __syncthreads();

    for (int i = t; i < Hh * 16; i += 512) {
        int row = i >> 4, seg = i & 15, grow = row0 + row;
        if (grow < Ee) {
            float4 a0 = *(const float4*)&u.acc[row][seg * 8];
            float4 a1 = *(const float4*)&u.acc[row][seg * 8 + 4];
            size_t o = (size_t)grow * Hh + seg * 8;
            uint4 bv;
            bv.x = pack2(a0.x, a0.y); bv.y = pack2(a0.z, a0.w);
            bv.z = pack2(a1.x, a1.y); bv.w = pack2(a1.z, a1.w);
            *(uint4*)&binput_bf[o] = bv;
            uint2 m;
            m.x = pack4f8(sigmoidf_(a0.x), sigmoidf_(a0.y),
                          sigmoidf_(a0.z), sigmoidf_(a0.w));
            m.y = pack4f8(sigmoidf_(a1.x), sigmoidf_(a1.y),
                          sigmoidf_(a1.z), sigmoidf_(a1.w));
            *(uint2*)&msg[o] = m;   // fp8 row = 128 B
        }
    }
}

// ---------------------------------------------------------------------------
// k_iter (MFMA, 256 thr, 64 rows): msg_out = fp8(sigmoid(binput + nei@W_h))
// v10's gather verbatim (16 lanes/row x 8B fp8 -> full 128B row per instr);
// MFMA A from LDS, B from GLOBAL frag-major wt_h; two-32-row-half epilogue.
// LDS: union(N 17408 B | acc32 16640 B) + sEG 2 KB = 19.4 KB.
// launch_bounds(256,4): VGPR cap 128 -- no forced spill (v11 lesson).
// ---------------------------------------------------------------------------
union IterSmem {
    u16 N[64 * KP];             // 17408 B
    float acc[32][ACC2];        // 16640 B
};

__global__ __launch_bounds__(256, 4) void k_iter(
    const u8* __restrict__ msg_in, const int* __restrict__ egraph,
    const u16* __restrict__ wt_h, const u16* __restrict__ binput_bf,
    u8* __restrict__ msg_out)
{
    __shared__ IterSmem u;
    __shared__ int sEG[64 * NBn];   // 2048 B
    const int t = threadIdx.x;
    const int row0 = blockIdx.x * 64;
    const int lane = t & 63, wid = t >> 6, l15 = lane & 15, l4 = lane >> 4;

    if (t < 128) {
        int r = row0 + (t >> 1);
        int4 v = make_int4(0, 0, 0, 0);
        if (r < Ee) v = ((const int4*)egraph)[r * 2 + (t & 1)];
        ((int4*)sEG)[t] = v;
    }
    __syncthreads();

    // gather: 16 lanes/row x 8B fp8; 16 rows per pass, 4 passes (v10 pattern)
    {
        const int s = t & 15, rl = t >> 4;
        #pragma unroll 2
        for (int pass = 0; pass < 4; ++pass) {
            int r = pass * 16 + rl;
            int grow = row0 + r;
            float a[8] = {0.f, 0.f, 0.f, 0.f, 0.f, 0.f, 0.f, 0.f};
            if (grow < Ee) {
                #pragma unroll
                for (int j = 0; j < NBn; ++j) {
                    int idx = sEG[r * NBn + j];
                    uint2 v = *(const uint2*)(msg_in + (size_t)idx * Hh + s * 8);
                    add8f8(a, v);
                }
            }
            uint4 o;
            o.x = pack2(a[0], a[1]); o.y = pack2(a[2], a[3]);
            o.z = pack2(a[4], a[5]); o.w = pack2(a[6], a[7]);
            *(uint4*)&u.N[r * KP + s * 8] = o;
        }
    }
    __syncthreads();

    // MFMA: A from LDS (rows wid*16..+15), B from global frag-major table
    f32x4 acc[8];
    #pragma unroll
    for (int b = 0; b < 8; ++b) acc[b] = (f32x4){0.f, 0.f, 0.f, 0.f};
    #pragma unroll
    for (int ks = 0; ks < 4; ++ks) {
        s16x8 a = *(const s16x8*)&u.N[(wid * 16 + l15) * KP + ks * 32 + l4 * 8];
        #pragma unroll
        for (int c = 0; c < 8; ++c) {
            s16x8 b = ((const s16x8*)wt_h)[(ks * 8 + c) * 64 + lane];
            acc[c] = __builtin_amdgcn_mfma_f32_16x16x32_bf16(a, b, acc[c], 0, 0, 0);
        }
    }
    __syncthreads();   // all LDS A-reads done -> union region reusable

    // epilogue: two 32-row halves through the union acc buffer
    #pragma unroll
    for (int h = 0; h < 2; ++h) {
        if ((wid >> 1) == h) {
            #pragma unroll
            for (int c = 0; c < 8; ++c)
                #pragma unroll
                for (int j = 0; j < 4; ++j)
                    u.acc[(wid & 1) * 16 + l4 * 4 + j][c * 16 + l15] = acc[c][j];
        }
        __syncthreads();
        for (int i = t; i < 32 * 16; i += 256) {
            int r = i >> 4, seg = i & 15;
            int g = row0 + h * 32 + r;
            if (g < Ee) {
                float4 a0 = *(const float4*)&u.acc[r][seg * 8];
                float4 a1 = *(const float4*)&u.acc[r][seg * 8 + 4];
                size_t o = (size_t)g * Hh + seg * 8;
                uint4 bv = *(const uint4*)&binput_bf[o];
                uint2 m;
                m.x = pack4f8(sigmoidf_(a0.x + bflo(bv.x)), sigmoidf_(a0.y + bfhi(bv.x)),
                              sigmoidf_(a0.z + bflo(bv.y)), sigmoidf_(a0.w + bfhi(bv.y)));
                m.y = pack4f8(sigmoidf_(a1.x + bflo(bv.z)), sigmoidf_(a1.y + bfhi(bv.z)),
                              sigmoidf_(a1.z + bflo(bv.w)), sigmoidf_(a1.w + bfhi(bv.w)));
                *(uint2*)&msg_out[o] = m;
            }
        }
        __syncthreads();
    }
}

// ---------------------------------------------------------------------------
// k_final (MFMA, 256 thr, 64 rows): hidden = bf16(sigmoid([feat|0|nei]@W_o+b))
// fp8 gather; B from GLOBAL frag-major wt_o.
// ---------------------------------------------------------------------------
union FinSmem {
    u16 A[64 * KO];         // 25600 B
    float acc[64][ACCW];    // 33792 B
};

__global__ __launch_bounds__(256, 4) void k_final(
    const u8* __restrict__ msg_in, const int* __restrict__ agraph,
    const float* __restrict__ features, const u16* __restrict__ wt_o,
    const float* __restrict__ b_o, u16* __restrict__ hidden)
{
    __shared__ FinSmem u;
    __shared__ int sAG[64 * NBn];   // 2048 B
    __shared__ float sBias[Hh];     // 512 B
    const int t = threadIdx.x;
    const int row0 = blockIdx.x * 64;
    const int nvalid = min(64, Nn - row0);

    {
        uint4 z = make_uint4(0, 0, 0, 0);
        for (int i = t; i < 64 * KO / 8; i += 256) ((uint4*)u.A)[i] = z;
    }
    if (t < 128) {
        int r = row0 + (t >> 1);
        int4 v = make_int4(0, 0, 0, 0);
        if (r < Nn) v = ((const int4*)agraph)[r * 2 + (t & 1)];
        ((int4*)sAG)[t] = v;
    }
    if (t < Hh / 4) ((float4*)sBias)[t] = ((const float4*)b_o)[t];
    __syncthreads();

    for (int i = t; i < nvalid * FFn; i += 256) {
        int r = i / FFn, k = i - r * FFn;
        u.A[r * KO + k] = f2bf(features[(size_t)row0 * FFn + i]);
    }
    {
        const int s = t & 15, rl = t >> 4;
        #pragma unroll 2
        for (int pass = 0; pass < 4; ++pass) {
            int r = pass * 16 + rl;
            int grow = row0 + r;
            float a[8] = {0.f, 0.f, 0.f, 0.f, 0.f, 0.f, 0.f, 0.f};
            if (grow < Nn) {
                #pragma unroll
                for (int j = 0; j < NBn; ++j) {
                    int idx = sAG[r * NBn + j];
                    uint2 v = *(const uint2*)(msg_in + (size_t)idx * Hh + s * 8);
                    add8f8(a, v);
                }
            }
            uint4 o;
            o.x = pack2(a[0], a[1]); o.y = pack2(a[2], a[3]);
            o.z = pack2(a[4], a[5]); o.w = pack2(a[6], a[7]);
            *(uint4*)&u.A[r * KO + 64 + s * 8] = o;
        }
    }
    __syncthreads();

    const int lane = t & 63, wid = t >> 6, l15 = lane & 15, l4 = lane >> 4;
    f32x4 acc[8];
    #pragma unroll
    for (int b = 0; b < 8; ++b) acc[b] = (f32x4){0.f, 0.f, 0.f, 0.f};

    #pragma unroll
    for (int ks = 0; ks < 6; ++ks) {
        s16x8 a = *(const s16x8*)&u.A[(wid * 16 + l15) * KO + ks * 32 + l4 * 8];
        #pragma unroll
        for (int c = 0; c < 8; ++c) {
            s16x8 b = ((const s16x8*)wt_o)[(ks * 8 + c) * 64 + lane];
            acc[c] = __builtin_amdgcn_mfma_f32_16x16x32_bf16(a, b, acc[c], 0, 0, 0);
        }
    }
    __syncthreads();   // A reads done -> union reusable

    #pragma unroll
    for (int c = 0; c < 8; ++c)
        #pragma unroll
        for (int j = 0; j < 4; ++j)
            u.acc[wid * 16 + l4 * 4 + j][c * 16 + l15] = acc[c][j];
    __syncthreads();

    for (int i = t; i < 64 * 16; i += 256) {
        int r = i >> 4, seg = i & 15, g = row0 + r;
        if (g < Nn) {
            float4 a0 = *(const float4*)&u.acc[r][seg * 8];
            float4 a1 = *(const float4*)&u.acc[r][seg * 8 + 4];
            const float* bb = &sBias[seg * 8];
            uint4 m;
            m.x = pack2(sigmoidf_(a0.x + bb[0]), sigmoidf_(a0.y + bb[1]));
            m.y = pack2(sigmoidf_(a0.z + bb[2]), sigmoidf_(a0.w + bb[3]));
            m.z = pack2(sigmoidf_(a1.x + bb[4]), sigmoidf_(a1.y + bb[5]));
            m.w = pack2(sigmoidf_(a1.z + bb[6]), sigmoidf_(a1.w + bb[7]));
            *(uint4*)&hidden[(size_t)g * Hh + seg * 8] = m;
        }
    }
}

// ---------------------------------------------------------------------------
// k_pool: segment mean over bf16 hidden. One block (128 threads) / molecule.
// ---------------------------------------------------------------------------
__global__ __launch_bounds__(128) void k_pool(
    const u16* __restrict__ hidden, const int* __restrict__ scope,
    float* __restrict__ out)
{
    const int b = blockIdx.x;
    const int t = threadIdx.x;
    const int start = scope[b * 2 + 0];
    const int len   = scope[b * 2 + 1];
    float acc = 0.f;
    for (int i = 0; i < len; ++i)
        acc += bf1(hidden[(size_t)(start + i) * Hh + t]);
    out[(size_t)b * Hh + t] = acc / (float)len;
}

// ---------------------------------------------------------------------------
extern "C" void kernel_launch(void* const* d_in, const int* in_sizes, int n_in,
                              void* d_out, int out_size, void* d_ws, size_t ws_size,
                              hipStream_t stream)
{
    const float* features = (const float*)d_in[0];
    const float* fedges   = (const float*)d_in[1];
    const int*   agraph   = (const int*)d_in[2];
    const int*   egraph   = (const int*)d_in[3];
    const int*   scope    = (const int*)d_in[4];
    const float* W_i      = (const float*)d_in[5];
    const float* W_h      = (const float*)d_in[6];
    const float* W_o      = (const float*)d_in[7];
    const float* b_o      = (const float*)d_in[8];
    float* out = (float*)d_out;

    // Workspace: binput bf16[E*128] | msg0 fp8[E*128] | msg1 fp8[E*128] | wt_h.
    // wt_i parks in msg1 (consumed by k_binput before iter0 writes msg1);
    // wt_o parks in binput region (prepped after the last k_iter);
    // hidden (bf16, 12.8 MB) lives in the final free fp8 plane (msg0, 19.2 MB).
    const size_t plane = (size_t)Ee * Hh;    // elements per plane
    u16* binput_bf = (u16*)d_ws;
    u8*  msg0 = (u8*)(binput_bf + plane);
    u8*  msg1 = msg0 + plane;
    u16* wt_h = (u16*)(msg1 + plane);        // 16384 u16
    u16* wt_i = (u16*)msg1;                  // 8192 u16 (parked)
    u16* wt_o = binput_bf;                   // 24576 u16 (parked, used last)

    k_prep1<<<(Hh * Hh + 16 * 512 + 255) / 256, 256, 0, stream>>>(W_h, W_i, wt_h, wt_i);

    k_binput<<<(Ee + 127) / 128, 512, 0, stream>>>(fedges, wt_i, binput_bf, msg0);

    const int eblocks64 = (Ee + 63) / 64;
    u8* src = msg0;
    u8* dst = msg1;
    for (int d = 0; d < ITERS; ++d) {
        k_iter<<<eblocks64, 256, 0, stream>>>(src, egraph, wt_h, binput_bf, dst);
        u8* tmp = src; src = dst; dst = tmp;
    }
    // final message in `src` (= msg1); binput now dead -> prep wt_o there.
    k_prep2<<<(48 * 512) / 256, 256, 0, stream>>>(W_o, wt_o);

    u16* hidden = (u16*)dst;   // = msg0 region (free, 19.2 MB >= 12.8 MB)
    const int nblocks = (Nn + 63) / 64;
    k_final<<<nblocks, 256, 0, stream>>>(src, agraph, features, wt_o, b_o, hidden);

    k_pool<<<Bm, 128, 0, stream>>>(hidden, scope, out);
}